// Round 16
// baseline (183.207 us; speedup 1.0000x reference)
//
#include <hip/hip_runtime.h>
#include <stdint.h>

// Problem constants: B=4, N=32768, K=16, nqueries=2048, stride=16.
// Geometry (R9/R14): 2 queries per wave, full 32K stream, 256-thr blocks,
// 4096 waves. Gate: dot-product expansion, s=|p|^2 shared by both queries
// (11 ops/pt/pair); conservative margin; accepted lanes re-verified with
// the EXACT numpy-ordered distance (bit-exact results).
//
// NEW vs R14: sched_barrier(0x7) after every load6 — R14's VGPR=56 proved
// the compiler SANK the 3-buffer pipeline's loads back to their uses
// (3 live buffers alone need 72 VGPR), silently reverting to ~1-step
// prefetch. 0x7 = ALU/SALU may cross, VMEM may not: loads stay pinned
// ~2 steps (~260 cyc) ahead of use, covering the ~200-cyc L2 latency.
// Verification signal: VGPR must rise to ~100-120.
#define NPTS  32768
#define NQ    2048
#define KNN   16
#define NB    4
#define BLOCK 256
#define WPB   4               // waves per block; 2 queries per wave
#define PPL   8               // points per lane per iteration
#define ITERS (NPTS / (64 * PPL))   // 64
#define GATE_MARGIN 5e-4f

__device__ __forceinline__ int dpp_shr1_i(int x) {
    // row_shr:1 within 16-lane rows; row-start lane keeps old (bound_ctrl=0)
    return __builtin_amdgcn_update_dpp(x, x, 0x111, 0xf, 0xf, false);
}
__device__ __forceinline__ float dpp_shr1_f(float x) {
    return __int_as_float(dpp_shr1_i(__float_as_int(x)));
}
__device__ __forceinline__ float readlane_f(float x, int l) {
    return __int_as_float(__builtin_amdgcn_readlane(__float_as_int(x), l));
}

// Pin VMEM at this program point; ALU/SALU remain free to schedule across.
__device__ __forceinline__ void pin_vmem() {
    __builtin_amdgcn_sched_barrier(0x7);
}

// Exact distributed top-16 for query T (0/1): sorted list (ascending by
// (dist,idx)) in lanes 16T..16T+15; lane 16T+15 holds the exact threshold
// tau. d is the EXACT numpy distance. th = tau + qnm is the conservative
// dot-product-gate threshold (qnm = -|q|^2 + margin).
template <int T>
__device__ __forceinline__ void insert_all(float d, int p, int lane,
                                           float& ld, int& li, float& tau,
                                           float& th, float qnm)
{
    unsigned long long rem = __ballot(d <= tau);
    while (rem) {
        const int srcl = __ffsll(rem) - 1;           // wave-uniform
        const float wd = readlane_f(d, srcl);
        const int   wi = __builtin_amdgcn_readlane(p, srcl);
        const bool less = (ld < wd) || (ld == wd && li < wi);
        const unsigned long long lm = __ballot(less);
        const int pos = __popc((unsigned)((lm >> (16 * T)) & 0xffffull));
        const float pld = dpp_shr1_f(ld);
        const int   pli = dpp_shr1_i(li);
        if ((lane >> 4) == T) {
            const int gl = lane & 15;
            if (gl == pos)      { ld = wd;  li = wi;  }
            else if (gl > pos)  { ld = pld; li = pli; }
        }
        tau = readlane_f(ld, 16 * T + 15);
        th  = tau + qnm;                             // gate threshold update
        rem &= rem - 1;
        if (rem) rem &= __ballot(d <= tau);          // re-gate survivors (exact)
    }
}

__device__ __forceinline__ void load6(float4 dst[6], const float4* p) {
    #pragma unroll
    for (int t = 0; t < 6; ++t) dst[t] = p[t];
}

// One 512-point step: 8 pts/lane; shared |p|^2 + per-query 3-fma gate;
// exact recompute + exact insert for accepted slots.
__device__ __forceinline__ void step2(const float4 c[6], int pb, int lane,
                                      float m2x0, float m2y0, float m2z0,
                                      float m2x1, float m2y1, float m2z1,
                                      float qx0, float qy0, float qz0,
                                      float qx1, float qy1, float qz1,
                                      float& ld, int& li,
                                      float& tau0, float& tau1,
                                      float& th0, float& th1,
                                      float qnm0, float qnm1)
{
    float px[PPL], py[PPL], pz[PPL];                 // pure register renames
    px[0] = c[0].x; py[0] = c[0].y; pz[0] = c[0].z;
    px[1] = c[0].w; py[1] = c[1].x; pz[1] = c[1].y;
    px[2] = c[1].z; py[2] = c[1].w; pz[2] = c[2].x;
    px[3] = c[2].y; py[3] = c[2].z; pz[3] = c[2].w;
    px[4] = c[3].x; py[4] = c[3].y; pz[4] = c[3].z;
    px[5] = c[3].w; py[5] = c[4].x; pz[5] = c[4].y;
    px[6] = c[4].z; py[6] = c[4].w; pz[6] = c[5].x;
    px[7] = c[5].y; py[7] = c[5].z; pz[7] = c[5].w;

    unsigned long long m0[PPL], m1[PPL], any = 0;
    #pragma unroll
    for (int j = 0; j < PPL; ++j) {                  // 8 independent chains
        const float s = __fmaf_rn(pz[j], pz[j],
                          __fmaf_rn(py[j], py[j], __fmul_rn(px[j], px[j])));
        float t0 = __fmaf_rn(px[j], m2x0, s);
        t0 = __fmaf_rn(py[j], m2y0, t0);
        t0 = __fmaf_rn(pz[j], m2z0, t0);
        m0[j] = __ballot(t0 <= th0);
        float t1 = __fmaf_rn(px[j], m2x1, s);
        t1 = __fmaf_rn(py[j], m2y1, t1);
        t1 = __fmaf_rn(pz[j], m2z1, t1);
        m1[j] = __ballot(t1 <= th1);
        any |= m0[j] | m1[j];
    }
    if (any) {
        #pragma unroll
        for (int j = 0; j < PPL; ++j) {
            if (m0[j]) {                             // exact numpy distance
                const float dx = __fadd_rn(px[j], -qx0);
                const float dy = __fadd_rn(py[j], -qy0);
                const float dz = __fadd_rn(pz[j], -qz0);
                const float d  = __fadd_rn(
                    __fadd_rn(__fmul_rn(dx, dx), __fmul_rn(dy, dy)),
                    __fmul_rn(dz, dz));
                insert_all<0>(d, pb + j, lane, ld, li, tau0, th0, qnm0);
            }
        }
        #pragma unroll
        for (int j = 0; j < PPL; ++j) {
            if (m1[j]) {
                const float dx = __fadd_rn(px[j], -qx1);
                const float dy = __fadd_rn(py[j], -qy1);
                const float dz = __fadd_rn(pz[j], -qz1);
                const float d  = __fadd_rn(
                    __fadd_rn(__fmul_rn(dx, dx), __fmul_rn(dy, dy)),
                    __fmul_rn(dz, dz));
                insert_all<1>(d, pb + j, lane, ld, li, tau1, th1, qnm1);
            }
        }
    }
}

// 1024 blocks x 4 waves = 4096 waves. launch_bounds(256,4) caps VGPR at
// 128; pipeline demand 3x24 + ~45 scalars ~= 117 fits (cap ABOVE demand,
// unlike the R3/R4 spill disasters where cap was below).
__global__ __launch_bounds__(BLOCK, 4) void knn_kernel(const float* __restrict__ xyz,
                                                       float* __restrict__ out_idx,
                                                       float* __restrict__ out_pts)
{
    const int tid  = threadIdx.x;
    const int lane = tid & 63;
    const int wv   = tid >> 6;
    const int w    = blockIdx.x * WPB + wv;          // wave id in [0, 4096)
    const int b    = w >> 10;
    const int pr   = w & 1023;                       // query pair
    const size_t base = (size_t)b * NPTS * 3;

    const int qp0 = pr << 5;                         // stride-16 subsample
    const float qx0 = xyz[base + 3 * qp0 + 0];
    const float qy0 = xyz[base + 3 * qp0 + 1];
    const float qz0 = xyz[base + 3 * qp0 + 2];
    const float qx1 = xyz[base + 3 * qp0 + 48];
    const float qy1 = xyz[base + 3 * qp0 + 49];
    const float qz1 = xyz[base + 3 * qp0 + 50];

    const int g0 = b * NQ + (pr << 1);
    if (lane == 0) {
        out_pts[3 * g0 + 0] = qx0;
        out_pts[3 * g0 + 1] = qy0;
        out_pts[3 * g0 + 2] = qz0;
        out_pts[3 * g0 + 3] = qx1;
        out_pts[3 * g0 + 4] = qy1;
        out_pts[3 * g0 + 5] = qz1;
    }

    // Gate constants: m2* = -2q*, qnm = -|q|^2 + margin.
    const float m2x0 = -2.0f * qx0, m2y0 = -2.0f * qy0, m2z0 = -2.0f * qz0;
    const float m2x1 = -2.0f * qx1, m2y1 = -2.0f * qy1, m2z1 = -2.0f * qz1;
    const float qnm0 = -(qx0 * qx0 + qy0 * qy0 + qz0 * qz0) + GATE_MARGIN;
    const float qnm1 = -(qx1 * qx1 + qy1 * qy1 + qz1 * qz1) + GATE_MARGIN;

    float ld = __builtin_inff();  int li = 0x7fffffff;
    float tau0 = __builtin_inff(), tau1 = __builtin_inff();
    float th0  = __builtin_inff(), th1  = __builtin_inff();

    // Lane's stream: 8 consecutive points (6 float4) per iteration.
    // Iteration i's lane data lives at lp0 + 384*i.
    const float4* lp0 = (const float4*)(xyz + base) + 6 * lane;

    // 3-stage software pipeline: buffer X holds iteration (3t + stage).
    float4 A[6], Bf[6], Cf[6];
    load6(A,  lp0);                                  // iter 0
    load6(Bf, lp0 + 384);                            // iter 1
    load6(Cf, lp0 + 768);                            // iter 2
    pin_vmem();                                      // prologue loads stay here
    const float4* ld_ptr = lp0 + 3 * 384;            // next load: iter 3
    int pb = PPL * lane;                             // point base, iter 0

    for (int it = 0; it < 21; ++it) {                // iters 0..62
        step2(A, pb, lane,
              m2x0, m2y0, m2z0, m2x1, m2y1, m2z1,
              qx0, qy0, qz0, qx1, qy1, qz1,
              ld, li, tau0, tau1, th0, th1, qnm0, qnm1);
        pb += 512;
        load6(A, ld_ptr);  ld_ptr += 384;            // iter 3it+3 (<=63: valid)
        pin_vmem();                                  // load can't sink past here
        step2(Bf, pb, lane,
              m2x0, m2y0, m2z0, m2x1, m2y1, m2z1,
              qx0, qy0, qz0, qx1, qy1, qz1,
              ld, li, tau0, tau1, th0, th1, qnm0, qnm1);
        pb += 512;
        if (it < 20) {
            load6(Bf, ld_ptr);                       // iter 3it+4 (guard OOB)
            pin_vmem();
        }
        ld_ptr += 384;
        step2(Cf, pb, lane,
              m2x0, m2y0, m2z0, m2x1, m2y1, m2z1,
              qx0, qy0, qz0, qx1, qy1, qz1,
              ld, li, tau0, tau1, th0, th1, qnm0, qnm1);
        pb += 512;
        if (it < 20) {
            load6(Cf, ld_ptr);                       // iter 3it+5 (guard OOB)
            pin_vmem();
        }
        ld_ptr += 384;
    }
    // epilogue: iter 63 (loaded into A during it=20)
    step2(A, pb, lane,
          m2x0, m2y0, m2z0, m2x1, m2y1, m2z1,
          qx0, qy0, qz0, qx1, qy1, qz1,
          ld, li, tau0, tau1, th0, th1, qnm0, qnm1);

    // lanes 0..15: q0 ranks 0..15; lanes 16..31: q1 ranks (g1 = g0+1)
    if (lane < 2 * KNN) {
        out_idx[(size_t)g0 * KNN + lane] = (float)li;
    }
}

extern "C" void kernel_launch(void* const* d_in, const int* in_sizes, int n_in,
                              void* d_out, int out_size, void* d_ws, size_t ws_size,
                              hipStream_t stream) {
    const float* xyz = (const float*)d_in[0];
    float* out = (float*)d_out;
    float* out_idx = out;                                 // NB*NQ*KNN floats
    float* out_pts = out + (size_t)NB * NQ * KNN;         // NB*NQ*3 floats

    const int blocks = (NB * NQ / 2) / WPB;               // 1024
    knn_kernel<<<blocks, BLOCK, 0, stream>>>(xyz, out_idx, out_pts);
}